// Round 1
// baseline (85.021 us; speedup 1.0000x reference)
//
#include <hip/hip_runtime.h>
#include <math.h>

#define IN_DIM 512
#define N_CLASSES 100
#define N_NODES 63
#define N_EST 16
#define N_LEAVES 64
#define BATCH 8192
#define TB 8          // batch rows per block
#define XPAD 516      // padded x row stride in floats (breaks stride-512 bank aliasing)

// ---------------- Kernel A: per-node argmax/max over IN_DIM ----------------
__global__ __launch_bounds__(64) void node_argmax_kernel(
    const float* __restrict__ T, float* __restrict__ tmax, int* __restrict__ dstar) {
  const int node = blockIdx.x;  // 0..1007 == e*63+n
  const float4* row = reinterpret_cast<const float4*>(T + (size_t)node * IN_DIM);
  const int lane = threadIdx.x;
  float best = -INFINITY;
  int bidx = 0;
#pragma unroll
  for (int i = 0; i < 2; ++i) {
    const int f4 = lane + 64 * i;
    const float4 v = row[f4];
    const int base = f4 * 4;
    if (v.x > best) { best = v.x; bidx = base; }
    if (v.y > best) { best = v.y; bidx = base + 1; }
    if (v.z > best) { best = v.z; bidx = base + 2; }
    if (v.w > best) { best = v.w; bidx = base + 3; }
  }
#pragma unroll
  for (int off = 32; off; off >>= 1) {
    const float ov = __shfl_xor(best, off);
    const int oi = __shfl_xor(bidx, off);
    if (ov > best || (ov == best && oi < bidx)) { best = ov; bidx = oi; }
  }
  if (lane == 0) {
    tmax[node] = best;
    dstar[node] = bidx;
  }
}

// ---------------- Kernel B: fused tree-products + GEMV + softmax ----------------
__global__ __launch_bounds__(256) void forest_kernel(
    const float* __restrict__ x, const float* __restrict__ L,
    const float* __restrict__ tmaxg, const int* __restrict__ dstarg,
    float* __restrict__ out) {
  __shared__ __align__(16) float lds_x[TB * XPAD];          // 16512 B
  __shared__ float lds_tmax[N_EST * N_NODES];               // 4032 B
  __shared__ int   lds_dst[N_EST * N_NODES];                // 4032 B
  __shared__ __align__(16) float lds_p[TB * 1024];          // 32768 B
  __shared__ float lds_y[TB * 128];                         // 4096 B

  const int tid = threadIdx.x;
  const int b0 = blockIdx.x * TB;

  // ---- phase 1: stage x rows (coalesced float4) + node table ----
  {
    const float4* xg = reinterpret_cast<const float4*>(x) + (size_t)b0 * (IN_DIM / 4);
#pragma unroll
    for (int i = 0; i < (TB * (IN_DIM / 4)) / 256; ++i) {
      const int idx = tid + i * 256;
      const int r = idx >> 7;       // 128 float4 per row
      const int c4 = idx & 127;
      *reinterpret_cast<float4*>(&lds_x[r * XPAD + c4 * 4]) = xg[r * (IN_DIM / 4) + c4];
    }
    for (int i = tid; i < N_EST * N_NODES; i += 256) {
      lds_tmax[i] = tmaxg[i];
      lds_dst[i] = dstarg[i];
    }
  }
  __syncthreads();

  // ---- phase 2: per-(row, estimator) level-wise tree product ----
  if (tid < TB * N_EST) {
    const int r = tid >> 4;
    const int e = tid & 15;
    float cum[64];
    cum[0] = 1.0f;
#pragma unroll
    for (int j = 1; j <= 6; ++j) {
      const int w = 1 << (j - 1);
#pragma unroll
      for (int q = w - 1; q >= 0; --q) {
        const int node = (w - 1) + q;  // heap index at level j
        const float tv = lds_tmax[e * N_NODES + node];
        const int dv = lds_dst[e * N_NODES + node];
        const float sv = floorf(tv - lds_x[r * XPAD + dv]);
        const float cprev = cum[q];
        cum[2 * q + 1] = cprev * (1.0f - sv);  // bit==1 branch
        cum[2 * q]     = cprev * sv;           // bit==0 branch
      }
    }
    // write p as float4 chunks, r-XOR swizzled to spread LDS banks
    const int swz = (r << 1);  // 0..14, stays inside the 16-chunk e-block
#pragma unroll
    for (int lq = 0; lq < 16; ++lq) {
      const int p4i = r * 256 + e * 16 + (lq ^ swz);
      reinterpret_cast<float4*>(lds_p)[p4i] =
          make_float4(cum[lq * 4], cum[lq * 4 + 1], cum[lq * 4 + 2], cum[lq * 4 + 3]);
    }
  }
  __syncthreads();

  // ---- phase 3: y[r][c] = sum_k p[r][k] * L[k][c] ----
  const int c = tid & 127;
  const int h = tid >> 7;  // rows h*4 .. h*4+3
  const int cc = (c < N_CLASSES) ? c : (N_CLASSES - 1);
  const float* Lp = L + cc;
  float acc[4] = {0.f, 0.f, 0.f, 0.f};
#pragma unroll 2
  for (int kc = 0; kc < 256; ++kc) {
    const int k = kc * 4;
    const float l0 = Lp[(k + 0) * N_CLASSES];
    const float l1 = Lp[(k + 1) * N_CLASSES];
    const float l2 = Lp[(k + 2) * N_CLASSES];
    const float l3 = Lp[(k + 3) * N_CLASSES];
#pragma unroll
    for (int rr = 0; rr < 4; ++rr) {
      const int r = h * 4 + rr;
      const float4 p4 = reinterpret_cast<const float4*>(lds_p)[r * 256 + (kc ^ (r << 1))];
      float a = acc[rr];
      a = fmaf(p4.x, l0, a);
      a = fmaf(p4.y, l1, a);
      a = fmaf(p4.z, l2, a);
      a = fmaf(p4.w, l3, a);
      acc[rr] = a;
    }
  }
  if (c < N_CLASSES) {
#pragma unroll
    for (int rr = 0; rr < 4; ++rr) lds_y[(h * 4 + rr) * 128 + c] = acc[rr];
  }
  __syncthreads();

  // ---- phase 4: row softmax (one wave per 2 rows) ----
  const int wv = tid >> 6;
  const int lane = tid & 63;
#pragma unroll
  for (int rr = 0; rr < 2; ++rr) {
    const int r = wv * 2 + rr;
    const float v1 = lds_y[r * 128 + lane];
    const float v2 = (lane + 64 < N_CLASSES) ? lds_y[r * 128 + lane + 64] : -INFINITY;
    float m = fmaxf(v1, v2);
#pragma unroll
    for (int off = 32; off; off >>= 1) m = fmaxf(m, __shfl_xor(m, off));
    const float e1 = __expf(v1 - m);
    const float e2 = (lane + 64 < N_CLASSES) ? __expf(v2 - m) : 0.0f;
    float ss = e1 + e2;
#pragma unroll
    for (int off = 32; off; off >>= 1) ss += __shfl_xor(ss, off);
    const float inv = 1.0f / ss;
    float* orow = out + (size_t)(b0 + r) * N_CLASSES;
    orow[lane] = e1 * inv;
    if (lane + 64 < N_CLASSES) orow[lane + 64] = e2 * inv;
  }
}

extern "C" void kernel_launch(void* const* d_in, const int* in_sizes, int n_in,
                              void* d_out, int out_size, void* d_ws, size_t ws_size,
                              hipStream_t stream) {
  const float* x = (const float*)d_in[0];   // (8192, 512)
  const float* T = (const float*)d_in[1];   // (16, 63, 512)
  const float* L = (const float*)d_in[2];   // (16, 64, 100)
  float* out = (float*)d_out;               // (8192, 100)

  float* tmax = (float*)d_ws;                                   // 1008 floats
  int* dstar = (int*)((char*)d_ws + N_EST * N_NODES * sizeof(float));  // 1008 ints

  node_argmax_kernel<<<N_EST * N_NODES, 64, 0, stream>>>(T, tmax, dstar);
  forest_kernel<<<BATCH / TB, 256, 0, stream>>>(x, L, tmax, dstar, out);
}